// Round 1
// baseline (389.329 us; speedup 1.0000x reference)
//
#include <hip/hip_runtime.h>
#include <math.h>

#define BN   32
#define CN   256
#define HWN  4096   // 64*64
#define AUXN 64
#define RANKN 64
#define HIDN 256
#define OSN  8

// ---------------- workspace layout (floats) ----------------
// g:        0       (8192)
// h:        8192    (8192)
// phi_c:    16384   (2048)
// m_base_c: 18432   (8192)
// s_m:      26624   (256)
// sig_c:    26880   (8192)
// y:        35072   (262144)   [b][2][4096]
// sig_s:    297216  (131072)   [b][4096]
#define WS_G    0
#define WS_H    8192
#define WS_PHIC 16384
#define WS_MBC  18432
#define WS_SM   26624
#define WS_SIGC 26880
#define WS_Y    35072
#define WS_SIGS 297216

// K1: g[b,c] = mean over 4096 spatial elements
__global__ __launch_bounds__(256) void k_gmean(const float* __restrict__ x,
                                               float* __restrict__ g) {
  int bc = blockIdx.x;                       // b*256 + c
  const float4* xv = (const float4*)(x + (size_t)bc * HWN);
  int t = threadIdx.x;
  float s = 0.f;
#pragma unroll
  for (int i = 0; i < 4; i++) {
    float4 v = xv[t + 256 * i];
    s += v.x + v.y + v.z + v.w;
  }
  for (int off = 32; off; off >>= 1) s += __shfl_down(s, off, 64);
  __shared__ float wred[4];
  if ((t & 63) == 0) wred[t >> 6] = s;
  __syncthreads();
  if (t == 0) g[bc] = (wred[0] + wred[1] + wred[2] + wred[3]) * (1.0f / 4096.0f);
}

// K2: per-batch MLP head: h, phi_c, phi_s, m_base_c, s_m
__global__ __launch_bounds__(256) void k_head(
    const float* __restrict__ g, const float* __restrict__ a,
    const float* __restrict__ W_pre, const float* __restrict__ b_pre,
    const float* __restrict__ W_bc,  const float* __restrict__ b_bc,
    const float* __restrict__ W_bs,  const float* __restrict__ b_bs,
    const float* __restrict__ W_pc,  const float* __restrict__ b_pc,
    const float* __restrict__ W_ps,  const float* __restrict__ b_ps,
    const float* __restrict__ W_Ws,  const float* __restrict__ b_Ws,
    float* __restrict__ h_out, float* __restrict__ phic_out,
    float* __restrict__ mbc_out, float* __restrict__ sm_out) {
  int b = blockIdx.x, t = threadIdx.x;
  __shared__ float in_s[320];
  __shared__ float h_s[256];
  __shared__ float phic_s[64], phis_s[64];
  __shared__ float red[512];
  in_s[t] = g[b * 256 + t];
  if (t < 64) in_s[256 + t] = a[b * 64 + t];
  __syncthreads();
  // h = relu([g,a] @ W_pre + b_pre)
  float acc = b_pre[t];
  for (int k = 0; k < 320; k++) acc = fmaf(in_s[k], W_pre[k * 256 + t], acc);
  float h = fmaxf(acc, 0.f);
  h_s[t] = h;
  h_out[b * 256 + t] = h;
  __syncthreads();
  // fourier features (only first half of u is used)
  if (t < 64) {
    int j = t & 31;
    const float* Wp = (t < 32) ? W_pc : W_ps;
    const float* bp = (t < 32) ? b_pc : b_ps;
    float u = bp[j];
    for (int k = 0; k < 256; k++) u = fmaf(h_s[k], Wp[k * 64 + j], u);
    float wj = 1.0f + (float)j * (3.14159265358979323846f - 1.0f) / 31.0f;
    float su = sinf(u * wj), cu = cosf(u * wj);
    float* ph = (t < 32) ? phic_s : phis_s;
    ph[j] = su;
    ph[32 + j] = cu;
  }
  __syncthreads();
  if (t < 64) phic_out[b * 64 + t] = phic_s[t];
  // m_base_c
  float mb = b_bc[t];
  for (int k = 0; k < 256; k++) mb = fmaf(h_s[k], W_bc[k * 256 + t], mb);
  mbc_out[b * 256 + t] = mb;
  // s-branch: Ws[b,s,r]*phi_s[r], 512 (s,r) pairs, 2 per thread
#pragma unroll
  for (int i = 0; i < 2; i++) {
    int idx = t + 256 * i;
    int s = idx >> 6, r = idx & 63;
    float v = b_Ws[s * 64 + r];
    for (int k = 0; k < 256; k++) v = fmaf(h_s[k], W_Ws[k * 512 + s * 64 + r], v);
    red[idx] = v * phis_s[r];
  }
  __syncthreads();
  if (t < 8) {
    float mbs = b_bs[t];
    for (int k = 0; k < 256; k++) mbs = fmaf(h_s[k], W_bs[k * 8 + t], mbs);
    float sum = 0.f;
    for (int r = 0; r < 64; r++) sum += red[t * 64 + r];
    sm_out[b * 8 + t] = mbs * sum;
  }
}

// K3: sig_c[b,c] — one block per channel c; W_Wc slab staged in LDS
__global__ __launch_bounds__(512) void k_cm(
    const float* __restrict__ W_Wc, const float* __restrict__ b_Wc,
    const float* __restrict__ h_ws, const float* __restrict__ phic_ws,
    const float* __restrict__ mbc_ws, float* __restrict__ sigc_out) {
  int c = blockIdx.x, t = threadIdx.x;
  __shared__ __align__(16) float wsl[16384];   // [k][r]  64 KB
  __shared__ float h_s[256 * 32];              // [k][b]  32 KB (b-major inner, conflict-free broadcast)
  __shared__ float phi_s[32 * 64];             // [b][r]   8 KB
  __shared__ float red[512];
  const float* col = W_Wc + (size_t)c * 64;
  for (int i = t; i < 16384; i += 512) {
    int k = i >> 6, r = i & 63;
    wsl[i] = col[(size_t)k * 16384 + r];
  }
  for (int i = t; i < 8192; i += 512) {
    int b = i >> 8, k = i & 255;
    h_s[k * 32 + b] = h_ws[i];
  }
  for (int i = t; i < 2048; i += 512) phi_s[i] = phic_ws[i];
  __syncthreads();
  int b = t >> 4, rq = t & 15;  // 32 batches x 16 r-quads = 512 tasks
  float4 q = {0.f, 0.f, 0.f, 0.f};
  const float4* wv = (const float4*)wsl;  // [k*16 + rq]
  for (int k = 0; k < 256; k++) {
    float4 w4 = wv[k * 16 + rq];
    float hb = h_s[k * 32 + b];
    q.x = fmaf(hb, w4.x, q.x);
    q.y = fmaf(hb, w4.y, q.y);
    q.z = fmaf(hb, w4.z, q.z);
    q.w = fmaf(hb, w4.w, q.w);
  }
  int r0 = rq * 4;
  float4 bw = ((const float4*)(b_Wc + (size_t)c * 64))[rq];
  float part = (q.x + bw.x) * phi_s[b * 64 + r0 + 0] +
               (q.y + bw.y) * phi_s[b * 64 + r0 + 1] +
               (q.z + bw.z) * phi_s[b * 64 + r0 + 2] +
               (q.w + bw.w) * phi_s[b * 64 + r0 + 3];
  red[t] = part;
  __syncthreads();
  if (t < 32) {
    float sum = 0.f;
    for (int i = 0; i < 16; i++) sum += red[t * 16 + i];
    float v = mbc_ws[t * 256 + c] * sum;
    sigc_out[t * 256 + c] = 1.f / (1.f + expf(-v));
  }
}

// K4: av/mx over channels -> y[b][2][4096]
__global__ __launch_bounds__(256) void k_avmx(const float* __restrict__ x,
                                              float* __restrict__ y) {
  int b = blockIdx.y;
  int px = blockIdx.x * 256 + threadIdx.x;
  const float* xb = x + (size_t)b * CN * HWN;
  float s = 0.f, m = -INFINITY;
#pragma unroll 8
  for (int c = 0; c < 256; c++) {
    float v = xb[(size_t)c * HWN + px];
    s += v;
    m = fmaxf(m, v);
  }
  y[(size_t)(b * 2 + 0) * HWN + px] = s * (1.0f / 256.0f);
  y[(size_t)(b * 2 + 1) * HWN + px] = m;
}

// K5a: 5-point stencil + sigmoid -> sig_s[b][4096]
__global__ __launch_bounds__(256) void k_conv(const float* __restrict__ y,
                                              const float* __restrict__ sm,
                                              float* __restrict__ sigs) {
  int b = blockIdx.x, t = threadIdx.x;
  __shared__ float ys[2 * 4096];
  __shared__ float pc[10];
  for (int i = t; i < 8192; i += 256) ys[i] = y[b * 8192 + i];
  if (t < 8) pc[t] = sm[b * 8 + t];
  __syncthreads();
  if (t == 0) {
    pc[8] = -(pc[0] + pc[1] + pc[2] + pc[3]);
    pc[9] = -(pc[4] + pc[5] + pc[6] + pc[7]);
  }
  __syncthreads();
  for (int px = t; px < 4096; px += 256) {
    int i = px >> 6, j = px & 63;
    float conv = 0.f;
#pragma unroll
    for (int k = 0; k < 2; k++) {
      const float* yk = ys + k * 4096;
      float up = (i > 0)  ? yk[px - 64] : 0.f;
      float dn = (i < 63) ? yk[px + 64] : 0.f;
      float lf = (j > 0)  ? yk[px - 1]  : 0.f;
      float rt = (j < 63) ? yk[px + 1]  : 0.f;
      conv += pc[k * 4 + 0] * up + pc[k * 4 + 1] * dn + pc[k * 4 + 2] * lf +
              pc[k * 4 + 3] * rt + pc[8 + k] * yk[px];
    }
    sigs[b * 4096 + px] = 1.f / (1.f + expf(-conv));
  }
}

// K5b: out = x * (1 + sig_c[b,c] + sig_s[b,px])
__global__ __launch_bounds__(256) void k_final(const float* __restrict__ x,
                                               const float* __restrict__ sigc,
                                               const float* __restrict__ sigs,
                                               float* __restrict__ out) {
  size_t idx4 = (size_t)blockIdx.x * 256 + threadIdx.x;
  size_t flat = idx4 * 4;
  int b = (int)(flat >> 20);
  int c = (int)((flat >> 12) & 255);
  int px = (int)(flat & 4095);
  float4 xv = ((const float4*)x)[idx4];
  float sc = 1.0f + sigc[b * 256 + c];
  float4 ss = ((const float4*)sigs)[((size_t)b * HWN + px) >> 2];
  float4 o;
  o.x = xv.x * (sc + ss.x);
  o.y = xv.y * (sc + ss.y);
  o.z = xv.z * (sc + ss.z);
  o.w = xv.w * (sc + ss.w);
  ((float4*)out)[idx4] = o;
}

extern "C" void kernel_launch(void* const* d_in, const int* in_sizes, int n_in,
                              void* d_out, int out_size, void* d_ws, size_t ws_size,
                              hipStream_t stream) {
  const float* x     = (const float*)d_in[0];
  const float* a     = (const float*)d_in[1];
  const float* W_pre = (const float*)d_in[2];
  const float* b_pre = (const float*)d_in[3];
  const float* W_bc  = (const float*)d_in[4];
  const float* b_bc  = (const float*)d_in[5];
  const float* W_bs  = (const float*)d_in[6];
  const float* b_bs  = (const float*)d_in[7];
  const float* W_pc  = (const float*)d_in[8];
  const float* b_pc  = (const float*)d_in[9];
  const float* W_ps  = (const float*)d_in[10];
  const float* b_ps  = (const float*)d_in[11];
  const float* W_Wc  = (const float*)d_in[12];
  const float* b_Wc  = (const float*)d_in[13];
  const float* W_Ws  = (const float*)d_in[14];
  const float* b_Ws  = (const float*)d_in[15];
  float* out = (float*)d_out;
  float* ws  = (float*)d_ws;

  float* g_ws    = ws + WS_G;
  float* h_ws    = ws + WS_H;
  float* phic_ws = ws + WS_PHIC;
  float* mbc_ws  = ws + WS_MBC;
  float* sm_ws   = ws + WS_SM;
  float* sigc_ws = ws + WS_SIGC;
  float* y_ws    = ws + WS_Y;
  float* sigs_ws = ws + WS_SIGS;

  k_gmean<<<BN * CN, 256, 0, stream>>>(x, g_ws);
  k_avmx<<<dim3(16, BN), 256, 0, stream>>>(x, y_ws);
  k_head<<<BN, 256, 0, stream>>>(g_ws, a, W_pre, b_pre, W_bc, b_bc, W_bs, b_bs,
                                 W_pc, b_pc, W_ps, b_ps, W_Ws, b_Ws,
                                 h_ws, phic_ws, mbc_ws, sm_ws);
  k_cm<<<CN, 512, 0, stream>>>(W_Wc, b_Wc, h_ws, phic_ws, mbc_ws, sigc_ws);
  k_conv<<<BN, 256, 0, stream>>>(y_ws, sm_ws, sigs_ws);
  k_final<<<(BN * CN * HWN) / 4 / 256, 256, 0, stream>>>(x, sigc_ws, sigs_ws, out);
}

// Round 2
// 366.463 us; speedup vs baseline: 1.0624x; 1.0624x over previous
//
#include <hip/hip_runtime.h>
#include <math.h>

#define BN   32
#define CN   256
#define HWN  4096   // 64*64
#define AUXN 64
#define RANKN 64
#define HIDN 256
#define OSN  8

// ---------------- workspace layout (floats) ----------------
#define WS_GPART 0        // [b][16][256] per-tile channel partial sums (131072)
#define WS_H     131072   // (8192)
#define WS_PHIC  139264   // (2048)
#define WS_MBC   141312   // (8192)
#define WS_SM    149504   // (256)
#define WS_SIGC  149760   // (8192)
#define WS_Y     157952   // [b][2][4096] (262144)
#define WS_SIGS  420096   // [b][4096] (131072)

#define TSTR 264  // padded LDS stride for the transpose tile (264%32=8 -> 2-way on stores)

// K1: single pass over x: per-px channel mean/max (y) + per-tile channel sums (gpart)
__global__ __launch_bounds__(256) void k_stats(const float* __restrict__ x,
                                               float* __restrict__ gpart,
                                               float* __restrict__ y) {
  int b = blockIdx.y, tile = blockIdx.x, t = threadIdx.x;
  int px = tile * 256 + t;
  const float* xb = x + (size_t)b * CN * HWN;
  __shared__ __align__(16) float tl[64 * TSTR];  // 67.6 KB -> 2 blocks/CU
  __shared__ float red[256];
  float s = 0.f, m = -INFINITY;
  float* gp = gpart + ((size_t)b * 16 + tile) * 256;
  for (int cc = 0; cc < 4; cc++) {
#pragma unroll 16
    for (int cl = 0; cl < 64; cl++) {
      float v = xb[(size_t)(cc * 64 + cl) * HWN + px];
      s += v;
      m = fmaxf(m, v);
      tl[cl * TSTR + t] = v;
    }
    __syncthreads();
    {  // transpose-reduce: 4 threads per channel, 64 px each, float4 LDS reads
      int cl = t >> 2, pg = t & 3;
      const float4* row = (const float4*)(tl + cl * TSTR + pg * 64);
      float4 acc = {0.f, 0.f, 0.f, 0.f};
#pragma unroll
      for (int j = 0; j < 16; j++) {
        float4 v4 = row[j];
        acc.x += v4.x; acc.y += v4.y; acc.z += v4.z; acc.w += v4.w;
      }
      red[t] = acc.x + acc.y + acc.z + acc.w;
    }
    __syncthreads();
    if (t < 64) gp[cc * 64 + t] = red[t * 4] + red[t * 4 + 1] + red[t * 4 + 2] + red[t * 4 + 3];
    __syncthreads();  // tl reused next chunk
  }
  y[(size_t)(b * 2 + 0) * HWN + px] = s * (1.0f / 256.0f);
  y[(size_t)(b * 2 + 1) * HWN + px] = m;
}

// K2: per-batch MLP head (includes the 16-way gpart reduce)
__global__ __launch_bounds__(256) void k_head(
    const float* __restrict__ gpart, const float* __restrict__ a,
    const float* __restrict__ W_pre, const float* __restrict__ b_pre,
    const float* __restrict__ W_bc,  const float* __restrict__ b_bc,
    const float* __restrict__ W_bs,  const float* __restrict__ b_bs,
    const float* __restrict__ W_pc,  const float* __restrict__ b_pc,
    const float* __restrict__ W_ps,  const float* __restrict__ b_ps,
    const float* __restrict__ W_Ws,  const float* __restrict__ b_Ws,
    float* __restrict__ h_out, float* __restrict__ phic_out,
    float* __restrict__ mbc_out, float* __restrict__ sm_out) {
  int b = blockIdx.x, t = threadIdx.x;
  __shared__ float in_s[320];
  __shared__ float h_s[256];
  __shared__ float phic_s[64], phis_s[64];
  __shared__ float red[512];
  {
    float gsum = 0.f;
#pragma unroll
    for (int tile = 0; tile < 16; tile++) gsum += gpart[((size_t)b * 16 + tile) * 256 + t];
    in_s[t] = gsum * (1.0f / 4096.0f);
  }
  if (t < 64) in_s[256 + t] = a[b * 64 + t];
  __syncthreads();
  // h = relu([g,a] @ W_pre + b_pre)
  float acc = b_pre[t];
  for (int k = 0; k < 320; k++) acc = fmaf(in_s[k], W_pre[k * 256 + t], acc);
  float h = fmaxf(acc, 0.f);
  h_s[t] = h;
  h_out[b * 256 + t] = h;
  __syncthreads();
  // fourier features (only first half of u is used)
  if (t < 64) {
    int j = t & 31;
    const float* Wp = (t < 32) ? W_pc : W_ps;
    const float* bp = (t < 32) ? b_pc : b_ps;
    float u = bp[j];
    for (int k = 0; k < 256; k++) u = fmaf(h_s[k], Wp[k * 64 + j], u);
    float wj = 1.0f + (float)j * (3.14159265358979323846f - 1.0f) / 31.0f;
    float su = sinf(u * wj), cu = cosf(u * wj);
    float* ph = (t < 32) ? phic_s : phis_s;
    ph[j] = su;
    ph[32 + j] = cu;
  }
  __syncthreads();
  if (t < 64) phic_out[b * 64 + t] = phic_s[t];
  // m_base_c
  float mb = b_bc[t];
  for (int k = 0; k < 256; k++) mb = fmaf(h_s[k], W_bc[k * 256 + t], mb);
  mbc_out[b * 256 + t] = mb;
  // s-branch: Ws[b,s,r]*phi_s[r]
#pragma unroll
  for (int i = 0; i < 2; i++) {
    int idx = t + 256 * i;
    int s = idx >> 6, r = idx & 63;
    float v = b_Ws[s * 64 + r];
    for (int k = 0; k < 256; k++) v = fmaf(h_s[k], W_Ws[k * 512 + s * 64 + r], v);
    red[idx] = v * phis_s[r];
  }
  __syncthreads();
  if (t < 8) {
    float mbs = b_bs[t];
    for (int k = 0; k < 256; k++) mbs = fmaf(h_s[k], W_bs[k * 8 + t], mbs);
    float sum = 0.f;
    for (int r = 0; r < 64; r++) sum += red[t * 64 + r];
    sm_out[b * 8 + t] = mbs * sum;
  }
}

// K3: merged sig_c (blocks 0..255, one per channel) + stencil sig_s (blocks 256..287)
__global__ __launch_bounds__(512) void k_cm_conv(
    const float* __restrict__ W_Wc, const float* __restrict__ b_Wc,
    const float* __restrict__ h_ws, const float* __restrict__ phic_ws,
    const float* __restrict__ mbc_ws, float* __restrict__ sigc_out,
    const float* __restrict__ y, const float* __restrict__ sm,
    float* __restrict__ sigs) {
  __shared__ __align__(16) float smem[27136];  // 106 KB union
  int t = threadIdx.x;
  if (blockIdx.x < 256) {
    int c = blockIdx.x;
    float* wsl   = smem;          // [k][r] 16384
    float* h_s   = smem + 16384;  // [k][b] 8192
    float* phi_s = smem + 24576;  // [b][r] 2048
    float* red   = smem + 26624;  // 512
    const float* col = W_Wc + (size_t)c * 64;
    for (int i = t; i < 16384; i += 512) {
      int k = i >> 6, r = i & 63;
      wsl[i] = col[(size_t)k * 16384 + r];
    }
    for (int i = t; i < 8192; i += 512) {
      int b = i >> 8, k = i & 255;
      h_s[k * 32 + b] = h_ws[i];
    }
    for (int i = t; i < 2048; i += 512) phi_s[i] = phic_ws[i];
    __syncthreads();
    int b = t >> 4, rq = t & 15;
    float4 q = {0.f, 0.f, 0.f, 0.f};
    const float4* wv = (const float4*)wsl;
    for (int k = 0; k < 256; k++) {
      float4 w4 = wv[k * 16 + rq];
      float hb = h_s[k * 32 + b];
      q.x = fmaf(hb, w4.x, q.x);
      q.y = fmaf(hb, w4.y, q.y);
      q.z = fmaf(hb, w4.z, q.z);
      q.w = fmaf(hb, w4.w, q.w);
    }
    int r0 = rq * 4;
    float4 bw = ((const float4*)(b_Wc + (size_t)c * 64))[rq];
    float part = (q.x + bw.x) * phi_s[b * 64 + r0 + 0] +
                 (q.y + bw.y) * phi_s[b * 64 + r0 + 1] +
                 (q.z + bw.z) * phi_s[b * 64 + r0 + 2] +
                 (q.w + bw.w) * phi_s[b * 64 + r0 + 3];
    red[t] = part;
    __syncthreads();
    if (t < 32) {
      float sum = 0.f;
      for (int i = 0; i < 16; i++) sum += red[t * 16 + i];
      float v = mbc_ws[t * 256 + c] * sum;
      sigc_out[t * 256 + c] = 1.f / (1.f + expf(-v));
    }
  } else {
    int b = blockIdx.x - 256;
    float* ys = smem;         // 8192
    float* pc = smem + 8192;  // 10
    for (int i = t; i < 8192; i += 512) ys[i] = y[b * 8192 + i];
    if (t < 8) pc[t] = sm[b * 8 + t];
    __syncthreads();
    if (t == 0) {
      pc[8] = -(pc[0] + pc[1] + pc[2] + pc[3]);
      pc[9] = -(pc[4] + pc[5] + pc[6] + pc[7]);
    }
    __syncthreads();
    for (int px = t; px < 4096; px += 512) {
      int i = px >> 6, j = px & 63;
      float conv = 0.f;
#pragma unroll
      for (int k = 0; k < 2; k++) {
        const float* yk = ys + k * 4096;
        float up = (i > 0)  ? yk[px - 64] : 0.f;
        float dn = (i < 63) ? yk[px + 64] : 0.f;
        float lf = (j > 0)  ? yk[px - 1]  : 0.f;
        float rt = (j < 63) ? yk[px + 1]  : 0.f;
        conv += pc[k * 4 + 0] * up + pc[k * 4 + 1] * dn + pc[k * 4 + 2] * lf +
                pc[k * 4 + 3] * rt + pc[8 + k] * yk[px];
      }
      sigs[b * 4096 + px] = 1.f / (1.f + expf(-conv));
    }
  }
}

// K4: out = x * (1 + sig_c[b,c] + sig_s[b,px])
__global__ __launch_bounds__(256) void k_final(const float* __restrict__ x,
                                               const float* __restrict__ sigc,
                                               const float* __restrict__ sigs,
                                               float* __restrict__ out) {
  size_t idx4 = (size_t)blockIdx.x * 256 + threadIdx.x;
  size_t flat = idx4 * 4;
  int b = (int)(flat >> 20);
  int c = (int)((flat >> 12) & 255);
  int px = (int)(flat & 4095);
  float4 xv = ((const float4*)x)[idx4];
  float sc = 1.0f + sigc[b * 256 + c];
  float4 ss = ((const float4*)sigs)[((size_t)b * HWN + px) >> 2];
  float4 o;
  o.x = xv.x * (sc + ss.x);
  o.y = xv.y * (sc + ss.y);
  o.z = xv.z * (sc + ss.z);
  o.w = xv.w * (sc + ss.w);
  ((float4*)out)[idx4] = o;
}

extern "C" void kernel_launch(void* const* d_in, const int* in_sizes, int n_in,
                              void* d_out, int out_size, void* d_ws, size_t ws_size,
                              hipStream_t stream) {
  const float* x     = (const float*)d_in[0];
  const float* a     = (const float*)d_in[1];
  const float* W_pre = (const float*)d_in[2];
  const float* b_pre = (const float*)d_in[3];
  const float* W_bc  = (const float*)d_in[4];
  const float* b_bc  = (const float*)d_in[5];
  const float* W_bs  = (const float*)d_in[6];
  const float* b_bs  = (const float*)d_in[7];
  const float* W_pc  = (const float*)d_in[8];
  const float* b_pc  = (const float*)d_in[9];
  const float* W_ps  = (const float*)d_in[10];
  const float* b_ps  = (const float*)d_in[11];
  const float* W_Wc  = (const float*)d_in[12];
  const float* b_Wc  = (const float*)d_in[13];
  const float* W_Ws  = (const float*)d_in[14];
  const float* b_Ws  = (const float*)d_in[15];
  float* out = (float*)d_out;
  float* ws  = (float*)d_ws;

  float* gpart_ws = ws + WS_GPART;
  float* h_ws     = ws + WS_H;
  float* phic_ws  = ws + WS_PHIC;
  float* mbc_ws   = ws + WS_MBC;
  float* sm_ws    = ws + WS_SM;
  float* sigc_ws  = ws + WS_SIGC;
  float* y_ws     = ws + WS_Y;
  float* sigs_ws  = ws + WS_SIGS;

  k_stats<<<dim3(16, BN), 256, 0, stream>>>(x, gpart_ws, y_ws);
  k_head<<<BN, 256, 0, stream>>>(gpart_ws, a, W_pre, b_pre, W_bc, b_bc, W_bs, b_bs,
                                 W_pc, b_pc, W_ps, b_ps, W_Ws, b_Ws,
                                 h_ws, phic_ws, mbc_ws, sm_ws);
  k_cm_conv<<<CN + BN, 512, 0, stream>>>(W_Wc, b_Wc, h_ws, phic_ws, mbc_ws, sigc_ws,
                                         y_ws, sm_ws, sigs_ws);
  k_final<<<(BN * CN * HWN) / 4 / 256, 256, 0, stream>>>(x, sigc_ws, sigs_ws, out);
}